// Round 5
// baseline (464.998 us; speedup 1.0000x reference)
//
#include <hip/hip_runtime.h>
#include <hip/hip_bf16.h>

#define N_TOKENS 16384
#define DIM      2048
#define NEXP     64
#define TOPK     8

// ---------------------------------------------------------------------------
// Kernel 1: router GEMM, fp32 (index stability requires fp32 logits; no
// fp32 MFMA on CDNA4 -> vector ALU, chip floor = 27.3 us).
// R2/R3/R4 all plateaued at ~84-95 us: every LDS-tiled variant oversubscribes
// the single per-CU LDS pipe (16 waves x 4 ds_read_b128 per 64 FMAs = 1.5x
// the 85 B/cyc pipe -> VALUBusy ceiling 67%, measured 38%).
// This version uses NO LDS and NO barriers: one thread per token, 64 fp32
// accumulators; A read directly from global (per-thread sequential k-walk,
// lines fully consumed via L1); B operands are wave-uniform -> compiler
// emits s_load (scalar pipe) and v_fmac_f32 acc, s_b, v_a. The VALU runs
// pure FMA; scalar/VMEM latency hidden by 16 waves/CU + e-level ILP.
// K split into 16 slabs (blockIdx.y) -> 1024 blocks = 4 blocks/CU.
// ---------------------------------------------------------------------------
__global__ __launch_bounds__(256, 4) void gemm_kernel(const float* __restrict__ A,
                                                      const float* __restrict__ W,
                                                      float* __restrict__ out,
                                                      int k_len) {
    const int tok = blockIdx.x * 256 + threadIdx.x;
    const int k0  = blockIdx.y * k_len;
    out += (size_t)blockIdx.y * N_TOKENS * NEXP + (size_t)tok * NEXP;

    const float* ap = A + (size_t)tok * DIM + k0;
    const float* wp = W + k0;

    float acc[NEXP] = {};

    for (int kc = 0; kc < k_len; kc += 16) {
        float4 a0 = *(const float4*)(ap + kc);
        float4 a1 = *(const float4*)(ap + kc + 4);
        float4 a2 = *(const float4*)(ap + kc + 8);
        float4 a3 = *(const float4*)(ap + kc + 12);
        float a[16] = {a0.x, a0.y, a0.z, a0.w, a1.x, a1.y, a1.z, a1.w,
                       a2.x, a2.y, a2.z, a2.w, a3.x, a3.y, a3.z, a3.w};
        const float* b = wp + kc;
        #pragma unroll
        for (int e = 0; e < NEXP; ++e) {
            const float* br = b + (size_t)e * DIM;   // uniform -> s_load
            #pragma unroll
            for (int j = 0; j < 16; ++j)
                acc[e] = fmaf(a[j], br[j], acc[e]);
        }
    }

    #pragma unroll
    for (int e = 0; e < NEXP; e += 4)
        *(float4*)(out + e) = make_float4(acc[e], acc[e + 1], acc[e + 2], acc[e + 3]);
}

// ---------------------------------------------------------------------------
// Kernel 2: slab-sum + softmax + top-8 via rank selection (lax.top_k
// semantics: sorted desc, ties -> lower index). 8192 waves, 2 tokens each.
// ---------------------------------------------------------------------------
__global__ __launch_bounds__(256) void topk_kernel(const float* __restrict__ logits,
                                                   int nslab,
                                                   float* __restrict__ out_w,
                                                   float* __restrict__ out_i,
                                                   float* __restrict__ cnt_ws,
                                                   float* __restrict__ sp_ws) {
    __shared__ float s_cnt[NEXP];
    __shared__ float s_sp[NEXP];
    if (threadIdx.x < NEXP) { s_cnt[threadIdx.x] = 0.f; s_sp[threadIdx.x] = 0.f; }
    __syncthreads();

    const int lane = threadIdx.x & 63;
    const int wave = blockIdx.x * 4 + (threadIdx.x >> 6);   // 0..8191
    const size_t slab_stride = (size_t)N_TOKENS * NEXP;

    float sp  = 0.f;
    float cnt = 0.f;

    for (int t = wave; t < N_TOKENS; t += 8192) {
        const float* p = logits + (size_t)t * NEXP + lane;
        float s0 = 0.f, s1 = 0.f, s2 = 0.f, s3 = 0.f;
        for (int s = 0; s < nslab; s += 4) {
            s0 += p[(size_t)(s + 0) * slab_stride];
            s1 += p[(size_t)(s + 1) * slab_stride];
            s2 += p[(size_t)(s + 2) * slab_stride];
            s3 += p[(size_t)(s + 3) * slab_stride];
        }
        float lg = (s0 + s1) + (s2 + s3);

        // softmax over 64 lanes
        float m = lg;
        #pragma unroll
        for (int off = 32; off; off >>= 1) m = fmaxf(m, __shfl_xor(m, off));
        float e = expf(lg - m);
        float ssum = e;
        #pragma unroll
        for (int off = 32; off; off >>= 1) ssum += __shfl_xor(ssum, off);
        float score = e / ssum;
        sp += score;

        // rank of this lane's score (64 independent, pipelined shuffles)
        int rank = 0;
        #pragma unroll
        for (int j = 0; j < 64; ++j) {
            float sj = __shfl(score, j);
            rank += (sj > score) || (sj == score && j < lane);
        }
        bool sel = rank < TOPK;

        float v = sel ? score : 0.f;
        #pragma unroll
        for (int off = 32; off; off >>= 1) v += __shfl_xor(v, off);

        if (sel) {
            out_w[(size_t)t * TOPK + rank] = score / v;
            out_i[(size_t)t * TOPK + rank] = (float)lane;
            cnt += 1.f;
        }
    }

    atomicAdd(&s_sp[lane], sp);
    atomicAdd(&s_cnt[lane], cnt);
    __syncthreads();
    if (threadIdx.x < 64)       atomicAdd(&cnt_ws[threadIdx.x], s_cnt[threadIdx.x]);
    else if (threadIdx.x < 128) atomicAdd(&sp_ws[threadIdx.x - 64], s_sp[threadIdx.x - 64]);
}

// ---------------------------------------------------------------------------
// Kernel 3: aux_loss = ALPHA * E * sum_e (cnt[e]/(N*K)) * (sum_prob[e]/N)
// ---------------------------------------------------------------------------
__global__ void finalize_kernel(const float* __restrict__ cnt_ws,
                                const float* __restrict__ sp_ws,
                                float* __restrict__ out_aux) {
    int lane = threadIdx.x;
    float v = (cnt_ws[lane] / (float)(N_TOKENS * TOPK)) *
              (sp_ws[lane] / (float)N_TOKENS);
    #pragma unroll
    for (int off = 32; off; off >>= 1) v += __shfl_xor(v, off);
    if (lane == 0) out_aux[0] = 0.001f * (float)NEXP * v;
}

extern "C" void kernel_launch(void* const* d_in, const int* in_sizes, int n_in,
                              void* d_out, int out_size, void* d_ws, size_t ws_size,
                              hipStream_t stream) {
    const float* A = (const float*)d_in[0];   // hidden_states (16384 x 2048)
    const float* W = (const float*)d_in[1];   // weight        (64 x 2048)
    float* out = (float*)d_out;

    const size_t logits_elems = (size_t)N_TOKENS * NEXP;
    const size_t logits_bytes = logits_elems * sizeof(float);

    int nslab = 4;
    if (ws_size >= 16 * logits_bytes + 1024)     nslab = 16;
    else if (ws_size >= 8 * logits_bytes + 1024) nslab = 8;

    float* l0     = (float*)d_ws;
    float* cnt_ws = (float*)((char*)d_ws + (size_t)nslab * logits_bytes);
    float* sp_ws  = cnt_ws + NEXP;

    hipMemsetAsync(cnt_ws, 0, 2 * NEXP * sizeof(float), stream);

    hipLaunchKernelGGL(gemm_kernel, dim3(N_TOKENS / 256, nslab), dim3(256), 0, stream,
                       A, W, l0, DIM / nslab);

    float* out_w = out;
    float* out_i = out + (size_t)N_TOKENS * TOPK;
    float* out_a = out + 2 * (size_t)N_TOKENS * TOPK;

    hipLaunchKernelGGL(topk_kernel, dim3(2048), dim3(256), 0, stream,
                       l0, nslab, out_w, out_i, cnt_ws, sp_ws);

    hipLaunchKernelGGL(finalize_kernel, dim3(1), dim3(64), 0, stream,
                       cnt_ws, sp_ws, out_a);
}

// Round 6
// 274.176 us; speedup vs baseline: 1.6960x; 1.6960x over previous
//
#include <hip/hip_runtime.h>
#include <hip/hip_bf16.h>

#define N_TOKENS 16384
#define DIM      2048
#define NEXP     64
#define TOPK     8
#define NSLAB    4
#define LOSCALE  2048.0f      // 2^11, exact power of two

typedef _Float16 half8  __attribute__((ext_vector_type(8)));
typedef float    floatx4 __attribute__((ext_vector_type(4)));

// ---------------------------------------------------------------------------
// Kernel 0: split W (64x2048 fp32) into f16 hi/lo planes.
//   whi = (f16)w;  wlo = (f16)((w - (f32)whi) * 2^11)   [scaled into normal
//   f16 range -> no denorm-flush risk in the MFMA lo products]
// ---------------------------------------------------------------------------
__global__ __launch_bounds__(256) void wprep_kernel(const float* __restrict__ W,
                                                    _Float16* __restrict__ Whi,
                                                    _Float16* __restrict__ Wlo) {
    int i = blockIdx.x * 256 + threadIdx.x;           // grid 512 -> 131072
    float w = W[i];
    _Float16 h = (_Float16)w;
    Whi[i] = h;
    Wlo[i] = (_Float16)((w - (float)h) * LOSCALE);
}

// ---------------------------------------------------------------------------
// Kernel 1: router GEMM via f16-split MFMA (fp32-accurate).
//   a*b ~= ah*bh + (ah*bl_s + al_s*bh)/2^11 ; dropped al*bl term ~2^-22|a||b|
//   is below fp32's own accumulation noise (which already passes the index
//   check), and fp32 MFMA accumulators make the sums exact per product.
// fp32-VALU GEMMs (R2-R5) plateaued at 84-95 us: 27 us chip FMA floor plus
// an LDS pipe that caps VALUBusy at ~67%. MFMA does the 12.9 GFLOP in ~6 us
// -> kernel is HBM-bound (134 MB A = 21 us floor). NO LDS, NO barriers:
//   A fp32 loaded directly in fragment layout A[m=lane&15][k=quad*8+j]
//   (two float4/lane -> 128 B segments), split hi/lo in-register;
//   B fragments B[n=lane&15][k=quad*8+j] read from the L2-hot W16 planes.
// Per wave: 32 tokens x 64 experts = 2x4 tiles 16x16x32, acc0 (hh) + acc1
// (scaled lo), 24 MFMA per 32-k chunk. grid = 128 x NSLAB=4 -> 512 blocks
// = 2 blocks/CU = 8 waves/CU. Logit partials per slab (4 MB each).
// ---------------------------------------------------------------------------
__global__ __launch_bounds__(256) void gemm_kernel(const float* __restrict__ A,
                                                   const _Float16* __restrict__ Whi,
                                                   const _Float16* __restrict__ Wlo,
                                                   float* __restrict__ out,
                                                   int k_len) {
    const int lane  = threadIdx.x & 63;
    const int wv    = threadIdx.x >> 6;
    const int row16 = lane & 15;
    const int quad  = lane >> 4;
    const int tbase = blockIdx.x * 128 + wv * 32;
    const int kbase = blockIdx.y * k_len;
    out += (size_t)blockIdx.y * N_TOKENS * NEXP;

    floatx4 acc0[2][4] = {};   // hi*hi
    floatx4 acc1[2][4] = {};   // hi*lo_s + lo_s*hi (carries 2^11 scale)

    for (int kc = kbase; kc < kbase + k_len; kc += 32) {
        // A fragments: fp32 -> f16 hi/lo split in-register
        half8 ah[2], al[2];
        #pragma unroll
        for (int mt = 0; mt < 2; ++mt) {
            const float* ap = A + (size_t)(tbase + mt * 16 + row16) * DIM + kc + quad * 8;
            float4 x0 = *(const float4*)ap;
            float4 x1 = *(const float4*)(ap + 4);
            float av[8] = {x0.x, x0.y, x0.z, x0.w, x1.x, x1.y, x1.z, x1.w};
            #pragma unroll
            for (int j = 0; j < 8; ++j) {
                _Float16 h = (_Float16)av[j];
                ah[mt][j] = h;
                al[mt][j] = (_Float16)((av[j] - (float)h) * LOSCALE);
            }
        }
        // B fragments from pre-split planes
        half8 bh[4], bl[4];
        #pragma unroll
        for (int nt = 0; nt < 4; ++nt) {
            size_t off = (size_t)(nt * 16 + row16) * DIM + kc + quad * 8;
            bh[nt] = *(const half8*)(Whi + off);
            bl[nt] = *(const half8*)(Wlo + off);
        }

        #pragma unroll
        for (int mt = 0; mt < 2; ++mt)
            #pragma unroll
            for (int nt = 0; nt < 4; ++nt) {
                acc0[mt][nt] = __builtin_amdgcn_mfma_f32_16x16x32_f16(ah[mt], bh[nt], acc0[mt][nt], 0, 0, 0);
                acc1[mt][nt] = __builtin_amdgcn_mfma_f32_16x16x32_f16(ah[mt], bl[nt], acc1[mt][nt], 0, 0, 0);
                acc1[mt][nt] = __builtin_amdgcn_mfma_f32_16x16x32_f16(al[mt], bh[nt], acc1[mt][nt], 0, 0, 0);
            }
    }

    // epilogue: logit = acc0 + acc1 * 2^-11 ; C layout col=lane&15 (expert),
    // row=quad*4+reg (token)  [m89-verified]
    const float inv = 1.0f / LOSCALE;
    #pragma unroll
    for (int mt = 0; mt < 2; ++mt)
        #pragma unroll
        for (int nt = 0; nt < 4; ++nt) {
            #pragma unroll
            for (int reg = 0; reg < 4; ++reg) {
                int tok = tbase + mt * 16 + quad * 4 + reg;
                out[(size_t)tok * NEXP + nt * 16 + row16] =
                    acc0[mt][nt][reg] + acc1[mt][nt][reg] * inv;
            }
        }
}

// ---------------------------------------------------------------------------
// Kernel 2: slab-sum + softmax + top-8 via rank selection (lax.top_k
// semantics: sorted desc, ties -> lower index). 8192 waves, 2 tokens each.
// ---------------------------------------------------------------------------
__global__ __launch_bounds__(256) void topk_kernel(const float* __restrict__ logits,
                                                   int nslab,
                                                   float* __restrict__ out_w,
                                                   float* __restrict__ out_i,
                                                   float* __restrict__ cnt_ws,
                                                   float* __restrict__ sp_ws) {
    __shared__ float s_cnt[NEXP];
    __shared__ float s_sp[NEXP];
    if (threadIdx.x < NEXP) { s_cnt[threadIdx.x] = 0.f; s_sp[threadIdx.x] = 0.f; }
    __syncthreads();

    const int lane = threadIdx.x & 63;
    const int wave = blockIdx.x * 4 + (threadIdx.x >> 6);   // 0..8191
    const size_t slab_stride = (size_t)N_TOKENS * NEXP;

    float sp  = 0.f;
    float cnt = 0.f;

    for (int t = wave; t < N_TOKENS; t += 8192) {
        const float* p = logits + (size_t)t * NEXP + lane;
        float s0 = 0.f, s1 = 0.f, s2 = 0.f, s3 = 0.f;
        for (int s = 0; s < nslab; s += 4) {
            s0 += p[(size_t)(s + 0) * slab_stride];
            s1 += p[(size_t)(s + 1) * slab_stride];
            s2 += p[(size_t)(s + 2) * slab_stride];
            s3 += p[(size_t)(s + 3) * slab_stride];
        }
        float lg = (s0 + s1) + (s2 + s3);

        // softmax over 64 lanes
        float m = lg;
        #pragma unroll
        for (int off = 32; off; off >>= 1) m = fmaxf(m, __shfl_xor(m, off));
        float e = expf(lg - m);
        float ssum = e;
        #pragma unroll
        for (int off = 32; off; off >>= 1) ssum += __shfl_xor(ssum, off);
        float score = e / ssum;
        sp += score;

        // rank of this lane's score (64 independent, pipelined shuffles)
        int rank = 0;
        #pragma unroll
        for (int j = 0; j < 64; ++j) {
            float sj = __shfl(score, j);
            rank += (sj > score) || (sj == score && j < lane);
        }
        bool sel = rank < TOPK;

        float v = sel ? score : 0.f;
        #pragma unroll
        for (int off = 32; off; off >>= 1) v += __shfl_xor(v, off);

        if (sel) {
            out_w[(size_t)t * TOPK + rank] = score / v;
            out_i[(size_t)t * TOPK + rank] = (float)lane;
            cnt += 1.f;
        }
    }

    atomicAdd(&s_sp[lane], sp);
    atomicAdd(&s_cnt[lane], cnt);
    __syncthreads();
    if (threadIdx.x < 64)       atomicAdd(&cnt_ws[threadIdx.x], s_cnt[threadIdx.x]);
    else if (threadIdx.x < 128) atomicAdd(&sp_ws[threadIdx.x - 64], s_sp[threadIdx.x - 64]);
}

// ---------------------------------------------------------------------------
// Kernel 3: aux_loss = ALPHA * E * sum_e (cnt[e]/(N*K)) * (sum_prob[e]/N)
// ---------------------------------------------------------------------------
__global__ void finalize_kernel(const float* __restrict__ cnt_ws,
                                const float* __restrict__ sp_ws,
                                float* __restrict__ out_aux) {
    int lane = threadIdx.x;
    float v = (cnt_ws[lane] / (float)(N_TOKENS * TOPK)) *
              (sp_ws[lane] / (float)N_TOKENS);
    #pragma unroll
    for (int off = 32; off; off >>= 1) v += __shfl_xor(v, off);
    if (lane == 0) out_aux[0] = 0.001f * (float)NEXP * v;
}

extern "C" void kernel_launch(void* const* d_in, const int* in_sizes, int n_in,
                              void* d_out, int out_size, void* d_ws, size_t ws_size,
                              hipStream_t stream) {
    const float* A = (const float*)d_in[0];   // hidden_states (16384 x 2048)
    const float* W = (const float*)d_in[1];   // weight        (64 x 2048)
    float* out = (float*)d_out;

    const size_t logits_elems = (size_t)N_TOKENS * NEXP;       // 1 Mi
    const size_t logits_bytes = logits_elems * sizeof(float);  // 4 MB

    float*    l0     = (float*)d_ws;                                  // 4 slabs
    _Float16* whi    = (_Float16*)((char*)d_ws + NSLAB * logits_bytes);
    _Float16* wlo    = whi + (size_t)NEXP * DIM;
    float*    cnt_ws = (float*)(wlo + (size_t)NEXP * DIM);
    float*    sp_ws  = cnt_ws + NEXP;

    hipMemsetAsync(cnt_ws, 0, 2 * NEXP * sizeof(float), stream);

    hipLaunchKernelGGL(wprep_kernel, dim3(NEXP * DIM / 256), dim3(256), 0, stream,
                       W, whi, wlo);

    hipLaunchKernelGGL(gemm_kernel, dim3(N_TOKENS / 128, NSLAB), dim3(256), 0, stream,
                       A, whi, wlo, l0, DIM / NSLAB);

    float* out_w = out;
    float* out_i = out + (size_t)N_TOKENS * TOPK;
    float* out_a = out + 2 * (size_t)N_TOKENS * TOPK;

    hipLaunchKernelGGL(topk_kernel, dim3(2048), dim3(256), 0, stream,
                       l0, NSLAB, out_w, out_i, cnt_ws, sp_ws);

    hipLaunchKernelGGL(finalize_kernel, dim3(1), dim3(64), 0, stream,
                       cnt_ws, sp_ws, out_a);
}

// Round 7
// 256.602 us; speedup vs baseline: 1.8121x; 1.0685x over previous
//
#include <hip/hip_runtime.h>
#include <hip/hip_bf16.h>

#define N_TOKENS 16384
#define DIM      2048
#define NEXP     64
#define TOPK     8
#define LOSCALE  2048.0f      // 2^11, exact power of two
#define NBLOCKS  512          // 32 tokens per block
#define LSTRIDE  66           // LDS token stride: (264*quad+row16)%32 -> <=2-way

typedef _Float16 half8   __attribute__((ext_vector_type(8)));
typedef float    floatx4 __attribute__((ext_vector_type(4)));

// ---------------------------------------------------------------------------
// Kernel 0: split W (64x2048 fp32) into f16 hi/lo planes.
//   whi = (f16)w;  wlo = (f16)((w - (f32)whi) * 2^11)  [scaled into normal
//   f16 range -> no denorm flush in the MFMA lo products]
// ---------------------------------------------------------------------------
__global__ __launch_bounds__(256) void wprep_kernel(const float* __restrict__ W,
                                                    _Float16* __restrict__ Whi,
                                                    _Float16* __restrict__ Wlo) {
    int i = blockIdx.x * 256 + threadIdx.x;           // grid 512 -> 131072
    float w = W[i];
    _Float16 h = (_Float16)w;
    Whi[i] = h;
    Wlo[i] = (_Float16)((w - (float)h) * LOSCALE);
}

// ---------------------------------------------------------------------------
// Fused kernel: MFMA router GEMM + softmax + top-8 + aux partials + (last
// block) aux finalize. Logits never touch HBM.
//   - 512 blocks x 4 waves; block owns 32 tokens; waves K-split (512 k each).
//   - K-loop: f16-split MFMA (a ~ ah + al/2^11; dropped ll term ~2^-22|a||b|,
//     below fp32's own accumulation noise -- validated index-exact in R6).
//     No LDS, no barriers; next chunk's loads issued before current MFMAs.
//   - Exchange: partial logits -> LDS [wave][tok][exp], token stride 66
//     (writes/reads <=2-way bank aliasing = free). One barrier.
//   - Epilogue: wave w does softmax + rank-select for tokens [8w,8w+8);
//     rank_i = #{j: s_j>s_i or (s_j==s_i and j<i)} = lax.top_k semantics.
//   - aux: per-lane cnt/sp -> LDS reduce -> global atomics (device scope);
//     last block (ticket) re-reads via atomics and writes aux_loss.
//     __syncthreads drains vmcnt -> block atomics complete before ticket.
// ---------------------------------------------------------------------------
__global__ __launch_bounds__(256) void moe_kernel(const float* __restrict__ A,
                                                  const _Float16* __restrict__ Whi,
                                                  const _Float16* __restrict__ Wlo,
                                                  float* __restrict__ out_w,
                                                  float* __restrict__ out_i,
                                                  float* __restrict__ out_aux,
                                                  float* __restrict__ cnt_ws,
                                                  float* __restrict__ sp_ws,
                                                  unsigned int* __restrict__ ticket) {
    __shared__ float lds[4 * 32 * LSTRIDE];
    __shared__ float s_cnt[NEXP];
    __shared__ float s_sp[NEXP];
    __shared__ int   s_last;

    const int lane  = threadIdx.x & 63;
    const int wv    = threadIdx.x >> 6;      // k-slab 0..3
    const int row16 = lane & 15;
    const int quad  = lane >> 4;
    const int tbase = blockIdx.x * 32;
    const int kbase = wv * 512;

    if (threadIdx.x < NEXP) { s_cnt[threadIdx.x] = 0.f; s_sp[threadIdx.x] = 0.f; }

    floatx4 acc0[2][4] = {};   // hi*hi
    floatx4 acc1[2][4] = {};   // hi*lo_s + lo_s*hi (carries 2^11)

    const float* ap0 = A + (size_t)(tbase + row16) * DIM + quad * 8;
    const float* ap1 = ap0 + (size_t)16 * DIM;
    const size_t boff = (size_t)row16 * DIM + quad * 8;

    // prologue loads (chunk 0)
    float4 ar[2][2];
    half8  bh[4], bl[4];
    ar[0][0] = *(const float4*)(ap0 + kbase);
    ar[0][1] = *(const float4*)(ap0 + kbase + 4);
    ar[1][0] = *(const float4*)(ap1 + kbase);
    ar[1][1] = *(const float4*)(ap1 + kbase + 4);
    #pragma unroll
    for (int nt = 0; nt < 4; ++nt) {
        bh[nt] = *(const half8*)(Whi + (size_t)nt * 16 * DIM + boff + kbase);
        bl[nt] = *(const half8*)(Wlo + (size_t)nt * 16 * DIM + boff + kbase);
    }

    for (int it = 0; it < 16; ++it) {
        // issue next chunk's loads first; they fly during split + MFMA
        float4 arn[2][2];
        half8  bhn[4], bln[4];
        if (it < 15) {
            int kc = kbase + (it + 1) * 32;
            arn[0][0] = *(const float4*)(ap0 + kc);
            arn[0][1] = *(const float4*)(ap0 + kc + 4);
            arn[1][0] = *(const float4*)(ap1 + kc);
            arn[1][1] = *(const float4*)(ap1 + kc + 4);
            #pragma unroll
            for (int nt = 0; nt < 4; ++nt) {
                bhn[nt] = *(const half8*)(Whi + (size_t)nt * 16 * DIM + boff + kc);
                bln[nt] = *(const half8*)(Wlo + (size_t)nt * 16 * DIM + boff + kc);
            }
        }

        // split current A f32 -> f16 hi/lo
        half8 ah[2], al[2];
        #pragma unroll
        for (int mt = 0; mt < 2; ++mt) {
            float av[8] = {ar[mt][0].x, ar[mt][0].y, ar[mt][0].z, ar[mt][0].w,
                           ar[mt][1].x, ar[mt][1].y, ar[mt][1].z, ar[mt][1].w};
            #pragma unroll
            for (int j = 0; j < 8; ++j) {
                _Float16 h = (_Float16)av[j];
                ah[mt][j] = h;
                al[mt][j] = (_Float16)((av[j] - (float)h) * LOSCALE);
            }
        }

        #pragma unroll
        for (int mt = 0; mt < 2; ++mt)
            #pragma unroll
            for (int nt = 0; nt < 4; ++nt) {
                acc0[mt][nt] = __builtin_amdgcn_mfma_f32_16x16x32_f16(ah[mt], bh[nt], acc0[mt][nt], 0, 0, 0);
                acc1[mt][nt] = __builtin_amdgcn_mfma_f32_16x16x32_f16(ah[mt], bl[nt], acc1[mt][nt], 0, 0, 0);
                acc1[mt][nt] = __builtin_amdgcn_mfma_f32_16x16x32_f16(al[mt], bh[nt], acc1[mt][nt], 0, 0, 0);
            }

        #pragma unroll
        for (int mt = 0; mt < 2; ++mt) { ar[mt][0] = arn[mt][0]; ar[mt][1] = arn[mt][1]; }
        #pragma unroll
        for (int nt = 0; nt < 4; ++nt) { bh[nt] = bhn[nt]; bl[nt] = bln[nt]; }
    }

    // partial logits -> LDS ; C layout: col=lane&15 (expert), row=quad*4+reg
    const float inv = 1.0f / LOSCALE;
    #pragma unroll
    for (int mt = 0; mt < 2; ++mt)
        #pragma unroll
        for (int nt = 0; nt < 4; ++nt)
            #pragma unroll
            for (int reg = 0; reg < 4; ++reg) {
                int tok = mt * 16 + quad * 4 + reg;
                lds[(wv * 32 + tok) * LSTRIDE + nt * 16 + row16] =
                    acc0[mt][nt][reg] + acc1[mt][nt][reg] * inv;
            }
    __syncthreads();

    // epilogue: wave wv handles tokens [wv*8, wv*8+8); lane = expert
    float sp = 0.f, cnt = 0.f;
    for (int i = 0; i < 8; ++i) {
        int t = wv * 8 + i;
        float lg = (lds[t * LSTRIDE + lane]              + lds[(32 + t) * LSTRIDE + lane])
                 + (lds[(64 + t) * LSTRIDE + lane]       + lds[(96 + t) * LSTRIDE + lane]);

        float m = lg;
        #pragma unroll
        for (int off = 32; off; off >>= 1) m = fmaxf(m, __shfl_xor(m, off));
        float e = expf(lg - m);
        float ssum = e;
        #pragma unroll
        for (int off = 32; off; off >>= 1) ssum += __shfl_xor(ssum, off);
        float score = e / ssum;
        sp += score;

        int rank = 0;
        #pragma unroll
        for (int j = 0; j < 64; ++j) {
            float sj = __shfl(score, j);
            rank += (sj > score) || (sj == score && j < lane);
        }
        bool sel = rank < TOPK;

        float v = sel ? score : 0.f;
        #pragma unroll
        for (int off = 32; off; off >>= 1) v += __shfl_xor(v, off);

        if (sel) {
            out_w[(size_t)(tbase + t) * TOPK + rank] = score / v;
            out_i[(size_t)(tbase + t) * TOPK + rank] = (float)lane;
            cnt += 1.f;
        }
    }

    atomicAdd(&s_sp[lane], sp);
    atomicAdd(&s_cnt[lane], cnt);
    __syncthreads();
    if (threadIdx.x < 64)       atomicAdd(&cnt_ws[threadIdx.x], s_cnt[threadIdx.x]);
    else if (threadIdx.x < 128) atomicAdd(&sp_ws[threadIdx.x - 64], s_sp[threadIdx.x - 64]);

    // __syncthreads drains vmcnt -> the block's global atomics are complete
    __threadfence();
    __syncthreads();
    if (threadIdx.x == 0)
        s_last = (atomicAdd(ticket, 1u) == (unsigned)(gridDim.x - 1));
    __syncthreads();
    if (s_last && threadIdx.x < 64) {
        float c = atomicAdd(&cnt_ws[threadIdx.x], 0.f);   // device-scope read
        float p = atomicAdd(&sp_ws[threadIdx.x], 0.f);
        float v = (c / (float)(N_TOKENS * TOPK)) * (p / (float)N_TOKENS);
        #pragma unroll
        for (int off = 32; off; off >>= 1) v += __shfl_xor(v, off);
        if (threadIdx.x == 0) out_aux[0] = 0.001f * (float)NEXP * v;
    }
}

extern "C" void kernel_launch(void* const* d_in, const int* in_sizes, int n_in,
                              void* d_out, int out_size, void* d_ws, size_t ws_size,
                              hipStream_t stream) {
    const float* A = (const float*)d_in[0];   // hidden_states (16384 x 2048)
    const float* W = (const float*)d_in[1];   // weight        (64 x 2048)
    float* out = (float*)d_out;

    _Float16*     whi    = (_Float16*)d_ws;
    _Float16*     wlo    = whi + (size_t)NEXP * DIM;
    float*        cnt_ws = (float*)(wlo + (size_t)NEXP * DIM);
    float*        sp_ws  = cnt_ws + NEXP;
    unsigned int* ticket = (unsigned int*)(sp_ws + NEXP);

    // zero cnt(256B) + sp(256B) + ticket(4B)
    hipMemsetAsync(cnt_ws, 0, 2 * NEXP * sizeof(float) + sizeof(unsigned int), stream);

    hipLaunchKernelGGL(wprep_kernel, dim3(NEXP * DIM / 256), dim3(256), 0, stream,
                       W, whi, wlo);

    float* out_w = out;
    float* out_i = out + (size_t)N_TOKENS * TOPK;
    float* out_a = out + 2 * (size_t)N_TOKENS * TOPK;

    hipLaunchKernelGGL(moe_kernel, dim3(NBLOCKS), dim3(256), 0, stream,
                       A, whi, wlo, out_w, out_i, out_a, cnt_ws, sp_ws, ticket);
}